// Round 12
// baseline (136.426 us; speedup 1.0000x reference)
//
#include <hip/hip_runtime.h>
#include <stdint.h>

#define NB 4
#define NS 2048
#define NHID 768
#define NNH 12
#define NHD 64
#define NBH 48
#define LOG2E 1.4426950408889634f

typedef __attribute__((ext_vector_type(8))) __bf16 bf16x8;
typedef __attribute__((ext_vector_type(4))) float f32x4;
typedef __attribute__((ext_vector_type(16))) float f32x16;

static __device__ __forceinline__ unsigned short f2bf(float f) {
  union { float f; uint32_t u; } v; v.f = f;
  uint32_t r = (v.u + 0x7FFFu + ((v.u >> 16) & 1u)) >> 16;  // RNE
  return (unsigned short)r;
}

static __device__ __forceinline__ unsigned int cvtpk(float lo, float hi) {
  unsigned int r;
  asm("v_cvt_pk_bf16_f32 %0, %1, %2" : "=v"(r) : "v"(lo), "v"(hi));
  return r;
}

#define GLDS(src, dst) __builtin_amdgcn_global_load_lds( \
    (const __attribute__((address_space(1))) void*)(src), \
    (__attribute__((address_space(3))) void*)(dst), 16, 0, 0)

// ---------------- kernel 0: fp32 -> bf16 (X and W concat) ----------------
__global__ void cvt_kernel(const float* __restrict__ X,
                           const float* __restrict__ Wq,
                           const float* __restrict__ Wk,
                           const float* __restrict__ Wv,
                           unsigned short* __restrict__ xb,
                           unsigned short* __restrict__ wb) {
  const int NX = NB * NS * NHID;   // 6291456
  const int NW = NHID * NHID;      // 589824
  int i = (blockIdx.x * blockDim.x + threadIdx.x) * 4;
  if (i < NX) {
    const float4 v = *(const float4*)(X + i);
    ushort4 o;
    o.x = f2bf(v.x); o.y = f2bf(v.y); o.z = f2bf(v.z); o.w = f2bf(v.w);
    *(ushort4*)(xb + i) = o;
  } else {
    int j = i - NX;
    const float* W; int jj;
    if (j < NW)          { W = Wq; jj = j; }
    else if (j < 2 * NW) { W = Wk; jj = j - NW; }
    else                 { W = Wv; jj = j - 2 * NW; }
    const float4 v = *(const float4*)(W + jj);
    ushort4 o;
    o.x = f2bf(v.x); o.y = f2bf(v.y); o.z = f2bf(v.z); o.w = f2bf(v.w);
    *(ushort4*)(wb + j) = o;
  }
}

// ---------------- kernel 1: fused QKV projection GEMM ----------------
// 128x128 tile, BK=64, 4 waves, global_load_lds(16B) into XOR-swizzled LDS.
__global__ void qkv_gemm(const unsigned short* __restrict__ xb,   // [8192][768] bf16
                         const unsigned short* __restrict__ wb,   // [3][768][768] bf16
                         const float* __restrict__ bq,
                         const float* __restrict__ bk,
                         const float* __restrict__ bv,
                         unsigned short* __restrict__ qw,   // [48][2048][64] (scaled 0.125*log2e)
                         unsigned short* __restrict__ kw,   // [48][2048][64]
                         unsigned short* __restrict__ vw) { // [48][64][2048] (transposed)
  __shared__ unsigned char As[128 * 128];   // [row][128B K-slab], swizzled
  __shared__ unsigned char Bs[128 * 128];
  const int tid = threadIdx.x;
  const int lane = tid & 63, wid = tid >> 6;
  const int l15 = lane & 15, l4 = lane >> 4;
  const int wr = wid >> 1, wc = wid & 1;
  const int mblock = blockIdx.x;   // 0..63
  const int ct = blockIdx.y;       // 0..17
  const int which = ct / 6, ctn = ct % 6;
  const int mbase = mblock * 128, nbase = ctn * 128;
  const unsigned short* Wb = wb + (size_t)which * NHID * NHID;

  const int srow = lane >> 3;                               // 0..7
  const int swz16 = ((lane & 7) * 16) ^ (srow << 4);        // < 128
  const unsigned char* agp = (const unsigned char*)xb + (size_t)mbase * (NHID * 2);
  const unsigned char* bgp = (const unsigned char*)Wb + (size_t)nbase * (NHID * 2);

  f32x4 acc[4][4];
  const f32x4 fzero = {0.f, 0.f, 0.f, 0.f};
#pragma unroll
  for (int mi = 0; mi < 4; ++mi)
#pragma unroll
    for (int ni = 0; ni < 4; ++ni) acc[mi][ni] = fzero;

  const int swzr = (l15 & 7) << 4;   // read-side XOR (row&7 == l15&7)

  for (int kt = 0; kt < 12; ++kt) {
    __syncthreads();
#pragma unroll
    for (int g = 0; g < 4; ++g) {
      int row = wid * 32 + g * 8 + srow;
      GLDS(agp + (size_t)row * (NHID * 2) + kt * 128 + swz16,
           As + (wid * 32 + g * 8) * 128);
      GLDS(bgp + (size_t)row * (NHID * 2) + kt * 128 + swz16,
           Bs + (wid * 32 + g * 8) * 128);
    }
    __syncthreads();   // vmcnt drained by barrier
#pragma unroll
    for (int ks = 0; ks < 2; ++ks) {
      bf16x8 af[4], bf[4];
#pragma unroll
      for (int mi = 0; mi < 4; ++mi)
        af[mi] = *(const bf16x8*)(As + (wr * 64 + mi * 16 + l15) * 128 +
                                  ((ks * 64 + l4 * 16) ^ swzr));
#pragma unroll
      for (int ni = 0; ni < 4; ++ni)
        bf[ni] = *(const bf16x8*)(Bs + (wc * 64 + ni * 16 + l15) * 128 +
                                  ((ks * 64 + l4 * 16) ^ swzr));
#pragma unroll
      for (int mi = 0; mi < 4; ++mi)
#pragma unroll
        for (int ni = 0; ni < 4; ++ni)
          acc[mi][ni] = __builtin_amdgcn_mfma_f32_16x16x32_bf16(af[mi], bf[ni], acc[mi][ni], 0, 0, 0);
    }
  }

  const float* bias = (which == 0) ? bq : (which == 1) ? bk : bv;
#pragma unroll
  for (int mi = 0; mi < 4; ++mi) {
    int row0 = mbase + wr * 64 + mi * 16 + l4 * 4;
    int b = row0 >> 11, s0 = row0 & 2047;
#pragma unroll
    for (int ni = 0; ni < 4; ++ni) {
      int col = nbase + wc * 64 + ni * 16 + l15;   // 0..767
      float bv_ = bias[col];
      int h = col >> 6, d = col & 63;
      if (which == 2) {
        ushort4 o;
        o.x = f2bf(acc[mi][ni][0] + bv_);
        o.y = f2bf(acc[mi][ni][1] + bv_);
        o.z = f2bf(acc[mi][ni][2] + bv_);
        o.w = f2bf(acc[mi][ni][3] + bv_);
        *(ushort4*)(vw + ((size_t)(b * NNH + h) * NHD + d) * NS + s0) = o;
      } else {
        unsigned short* dst = (which == 0) ? qw : kw;
        // Q carries 1/sqrt(64) * log2e so scores come out in log2 units
        float sc = (which == 0) ? 0.125f * LOG2E : 1.0f;
#pragma unroll
        for (int r = 0; r < 4; ++r) {
          float val = (acc[mi][ni][r] + bv_) * sc;
          dst[((size_t)(b * NNH + h) * NS + (s0 + r)) * NHD + d] = f2bf(val);
        }
      }
    }
  }
}

// ---------------- attn helpers (fully inlined; refs resolve to registers) ----------------
// QK^T of tile t: P0/P1 = cmask-C-init + S^T for keys [t*64, t*64+64)
static __device__ __forceinline__ void qkt_tile(
    int t, const unsigned char* ldsb, const float* cmask,
    int hi, int l31, const int* colA, const bf16x8* qf,
    f32x16& P0, f32x16& P1) {
  const float* cmt = cmask + t * 64;
  const unsigned char* kl = ldsb + (t & 1) * 8192;
#pragma unroll
  for (int c = 0; c < 4; ++c) {
    float4 cv = *(const float4*)(cmt + c * 8 + hi * 4);
    P0[c * 4 + 0] = cv.x; P0[c * 4 + 1] = cv.y;
    P0[c * 4 + 2] = cv.z; P0[c * 4 + 3] = cv.w;
    float4 cw = *(const float4*)(cmt + 32 + c * 8 + hi * 4);
    P1[c * 4 + 0] = cw.x; P1[c * 4 + 1] = cw.y;
    P1[c * 4 + 2] = cw.z; P1[c * 4 + 3] = cw.w;
  }
#pragma unroll
  for (int dk = 0; dk < 4; ++dk) {
    bf16x8 kf0 = *(const bf16x8*)(kl + l31 * 128 + colA[dk]);
    P0 = __builtin_amdgcn_mfma_f32_32x32x16_bf16(kf0, qf[dk], P0, 0, 0, 0);
    bf16x8 kf1 = *(const bf16x8*)(kl + (32 + l31) * 128 + colA[dk]);
    P1 = __builtin_amdgcn_mfma_f32_32x32x16_bf16(kf1, qf[dk], P1, 0, 0, 0);
  }
}

// softmax (static bias) + PV of tile t. P consumed in place.
static __device__ __forceinline__ void smpv_tile(
    int t, const unsigned char* ldsb, int hi, int l31, const int* colA,
    float& mrun, float& lrun, f32x16& P0, f32x16& P1,
    f32x16& O0, f32x16& O1) {
  if (mrun != 8.0f) {   // only if the cold guard ever fired (cmask bakes -8)
    float corr = mrun - 8.0f;
#pragma unroll
    for (int e = 0; e < 16; ++e) { P0[e] -= corr; P1[e] -= corr; }
  }
#pragma unroll
  for (int e = 0; e < 16; ++e) {
    P0[e] = __builtin_amdgcn_exp2f(P0[e]);
    P1[e] = __builtin_amdgcn_exp2f(P1[e]);
  }
  float s8[8];
#pragma unroll
  for (int e = 0; e < 8; ++e)
    s8[e] = (P0[e] + P0[e + 8]) + (P1[e] + P1[e + 8]);
  float rsum = ((s8[0] + s8[1]) + (s8[2] + s8[3])) +
               ((s8[4] + s8[5]) + (s8[6] + s8[7]));
  int guard = 0;
  while (!__all(rsum <= 0x1p40f) && ++guard < 4) {   // cold exact pow2 rescale
    const float c = 0x1p-64f;
#pragma unroll
    for (int e = 0; e < 16; ++e) { P0[e] *= c; P1[e] *= c; O0[e] *= c; O1[e] *= c; }
    lrun *= c; rsum *= c; mrun += 64.0f;
  }
  lrun += rsum;

  const unsigned char* vl = ldsb + 16384 + (t & 1) * 8192;
  // PV: af[ks][j] = P[q=l31][key = ks*16 + hi*8 + j] via cvtpk + permlane32_swap
  // (permlane construction proven ≡ verified shfl path: r2 vs r3 bit-identical)
#pragma unroll
  for (int ks = 0; ks < 2; ++ks) {
    const int cl = (2 * ks) & 3, ch = cl + 1;
    unsigned int wa0 = cvtpk(P0[cl * 4 + 0], P0[cl * 4 + 1]);
    unsigned int wa1 = cvtpk(P0[cl * 4 + 2], P0[cl * 4 + 3]);
    unsigned int wb0 = cvtpk(P0[ch * 4 + 0], P0[ch * 4 + 1]);
    unsigned int wb1 = cvtpk(P0[ch * 4 + 2], P0[ch * 4 + 3]);
    auto s0 = __builtin_amdgcn_permlane32_swap(wa0, wb0, false, false);
    auto s1 = __builtin_amdgcn_permlane32_swap(wa1, wb1, false, false);
    union { unsigned int u[4]; bf16x8 v; } afu;
    afu.u[0] = s0[0]; afu.u[2] = s0[1];
    afu.u[1] = s1[0]; afu.u[3] = s1[1];
    bf16x8 vf0 = *(const bf16x8*)(vl + l31 * 128 + colA[ks]);
    bf16x8 vf1 = *(const bf16x8*)(vl + (32 + l31) * 128 + colA[ks]);
    O0 = __builtin_amdgcn_mfma_f32_32x32x16_bf16(afu.v, vf0, O0, 0, 0, 0);
    O1 = __builtin_amdgcn_mfma_f32_32x32x16_bf16(afu.v, vf1, O1, 0, 0, 0);
  }
#pragma unroll
  for (int ks = 2; ks < 4; ++ks) {
    const int cl = (2 * ks) & 3, ch = cl + 1;
    unsigned int wa0 = cvtpk(P1[cl * 4 + 0], P1[cl * 4 + 1]);
    unsigned int wa1 = cvtpk(P1[cl * 4 + 2], P1[cl * 4 + 3]);
    unsigned int wb0 = cvtpk(P1[ch * 4 + 0], P1[ch * 4 + 1]);
    unsigned int wb1 = cvtpk(P1[ch * 4 + 2], P1[ch * 4 + 3]);
    auto s0 = __builtin_amdgcn_permlane32_swap(wa0, wb0, false, false);
    auto s1 = __builtin_amdgcn_permlane32_swap(wa1, wb1, false, false);
    union { unsigned int u[4]; bf16x8 v; } afu;
    afu.u[0] = s0[0]; afu.u[2] = s0[1];
    afu.u[1] = s1[0]; afu.u[3] = s1[1];
    bf16x8 vf0 = *(const bf16x8*)(vl + l31 * 128 + colA[ks]);
    bf16x8 vf1 = *(const bf16x8*)(vl + (32 + l31) * 128 + colA[ks]);
    O0 = __builtin_amdgcn_mfma_f32_32x32x16_bf16(afu.v, vf0, O0, 0, 0, 0);
    O1 = __builtin_amdgcn_mfma_f32_32x32x16_bf16(afu.v, vf1, O1, 0, 0, 0);
  }
}

// ---------------- kernel 2: flash attention, 4-wave 2-deep pipelined ----------------
// grid 768 (XCD-remapped), 256 threads = 4 waves, each wave owns 32 q rows,
// block streams ALL 2048 keys (32 tiles, no split-KV, no merge).
// 2-deep software pipeline: iteration t runs QK^T(t+1) (MFMA) interleaved with
// softmax(t) (VALU) and PV(t) (MFMA) — within-wave MFMA/VALU overlap, breaking
// the phase lockstep that made r5-r11 time-invariant. pA/pB statically swapped.
// LDS 40KB: K dbuf 16K + V dbuf 16K + cmask 8K -> 3-4 blocks/CU; grid = 3*256.
// launch_bounds(256,2): cap 256 regs — no forced spill (r6/r9 lesson).
__global__ __launch_bounds__(256, 2)
void attn_kernel(const unsigned short* __restrict__ qw,
                 const unsigned short* __restrict__ kw,
                 const unsigned short* __restrict__ vw,
                 const float* __restrict__ mask,
                 float* __restrict__ out) {
  __shared__ unsigned char lds[40960];   // [K0|K1|V0|V1] x 8KB + cmask 8KB

  const int tid = threadIdx.x;
  const int lane = tid & 63, wid = tid >> 6;       // wid 0..3
  const int l31 = lane & 31, hi = lane >> 5;
  const int r_ = blockIdx.x;           // 0..767
  const int j_ = r_ >> 3, xcd = r_ & 7;
  const int bh = xcd * 6 + (j_ % 6);   // bh-major per XCD
  const int qb = j_ / 6;               // 0..15
  const int b = bh / NNH, h = bh % NNH;
  const size_t bh_off = (size_t)bh * NS * NHD;
  const int qbase = qb * 128 + wid * 32;

  float* const cmask = (float*)(lds + 32768);      // [2048] = mask*log2e - 8

  {  // precompute C-init values (8 per thread)
    const float* mrow = mask + (size_t)b * NS;
    float4 m0 = *(const float4*)(mrow + tid * 8);
    float4 m1 = *(const float4*)(mrow + tid * 8 + 4);
    float4 c0, c1;
    c0.x = fmaf(m0.x, LOG2E, -8.0f); c0.y = fmaf(m0.y, LOG2E, -8.0f);
    c0.z = fmaf(m0.z, LOG2E, -8.0f); c0.w = fmaf(m0.w, LOG2E, -8.0f);
    c1.x = fmaf(m1.x, LOG2E, -8.0f); c1.y = fmaf(m1.y, LOG2E, -8.0f);
    c1.z = fmaf(m1.z, LOG2E, -8.0f); c1.w = fmaf(m1.w, LOG2E, -8.0f);
    *(float4*)(cmask + tid * 8) = c0;
    *(float4*)(cmask + tid * 8 + 4) = c1;
  }

  // hoist Q B-fragments: Q[q = qbase+l31][d = dk*16 + hi*8 + j]
  bf16x8 qf[4];
#pragma unroll
  for (int dk = 0; dk < 4; ++dk)
    qf[dk] = *(const bf16x8*)(qw + bh_off + (size_t)(qbase + l31) * NHD + dk * 16 + hi * 8);

  // staging: per-lane pre-swizzled global offsets (LDS dest is linear)
  const int swz16 = ((lane & 7) * 16) ^ (((lane >> 3) & 7) << 4);
  const unsigned char* kgp = (const unsigned char*)(kw + bh_off);
  const unsigned char* vgp = (const unsigned char*)(vw + bh_off);
  const int kst = (lane >> 3) * 128 + swz16;                 // within K row-block
  const size_t vst = (size_t)(lane >> 3) * (NS * 2) + swz16; // V^T rows stride 4096B
  const int c0 = wid * 2, c1 = c0 + 1;                       // this wave's 2 chunks

  // ds_read col offsets (swizzled); row&7 == l31&7 for all our reads
  const int swzr = (l31 & 7) << 4;
  int colA[4];
#pragma unroll
  for (int i = 0; i < 4; ++i) colA[i] = (i * 32 + hi * 16) ^ swzr;

  f32x16 oacc0, oacc1, pA0, pA1, pB0, pB1;
#pragma unroll
  for (int e = 0; e < 16; ++e) { oacc0[e] = 0.f; oacc1[e] = 0.f; }
  float mrun = 8.0f;   // static log2-domain exponent bias
  float lrun = 0.f;    // per-lane PARTIAL; partner-combined at end

#define STAGE_K(t_) do { \
    size_t kk = (size_t)(t_) * 64; \
    unsigned char* kd = lds + ((t_) & 1) * 8192; \
    GLDS(kgp + kk * 128 + c0 * 1024 + kst, kd + c0 * 1024); \
    GLDS(kgp + kk * 128 + c1 * 1024 + kst, kd + c1 * 1024); \
  } while (0)
#define STAGE_V(t_) do { \
    size_t kk = (size_t)(t_) * 64; \
    unsigned char* vd = lds + 16384 + ((t_) & 1) * 8192; \
    GLDS(vgp + (size_t)c0 * 8 * (NS * 2) + kk * 2 + vst, vd + c0 * 1024); \
    GLDS(vgp + (size_t)c1 * 8 * (NS * 2) + kk * 2 + vst, vd + c1 * 1024); \
  } while (0)

  STAGE_K(0);
  STAGE_V(0);
  __syncthreads();   // cmask + K(0) + V(0) visible

  qkt_tile(0, lds, cmask, hi, l31, colA, qf, pA0, pA1);
  STAGE_K(1);        // kbuf1; QK^T(0) read kbuf0

  for (int tp = 0; tp < 16; ++tp) {
    const int t = tp * 2;
    // ---- iteration t (even): consume pA, produce pB = S(t+1) ----
    __syncthreads();                 // K(t+1), V(t) visible; kbuf[t&1], vbuf[(t-1)&1] free
    if (t + 1 < 32) STAGE_V(t + 1);  // -> vbuf[(t+1)&1]
    if (t + 2 < 32) STAGE_K(t + 2);  // -> kbuf[t&1]
    if (t + 1 < 32)
      qkt_tile(t + 1, lds, cmask, hi, l31, colA, qf, pB0, pB1);
    smpv_tile(t, lds, hi, l31, colA, mrun, lrun, pA0, pA1, oacc0, oacc1);

    // ---- iteration t+1 (odd): consume pB, produce pA = S(t+2) ----
    __syncthreads();
    if (t + 2 < 32) STAGE_V(t + 2);
    if (t + 3 < 32) STAGE_K(t + 3);
    if (t + 2 < 32)
      qkt_tile(t + 2, lds, cmask, hi, l31, colA, qf, pA0, pA1);
    smpv_tile(t + 1, lds, hi, l31, colA, mrun, lrun, pB0, pB1, oacc0, oacc1);
  }

  // combine partner-lane partial sums once
  lrun += __shfl_xor(lrun, 32);
  float invl = 1.0f / lrun;          // softmax domain (q = l31)

  // epilogue: route 1/l to O-domain rows, store fp32 merge-heads layout
#pragma unroll
  for (int reg = 0; reg < 16; ++reg) {
    int q_local = (reg & 3) + 8 * (reg >> 2) + 4 * hi;
    float inv_r = __shfl(invl, q_local);
    int q = qbase + q_local;
    out[((size_t)b * NS + q) * NHID + h * 64 + l31]      = oacc0[reg] * inv_r;
    out[((size_t)b * NS + q) * NHID + h * 64 + 32 + l31] = oacc1[reg] * inv_r;
  }
#undef STAGE_K
#undef STAGE_V
}

extern "C" void kernel_launch(void* const* d_in, const int* in_sizes, int n_in,
                              void* d_out, int out_size, void* d_ws, size_t ws_size,
                              hipStream_t stream) {
  const float* X    = (const float*)d_in[0];
  const float* mask = (const float*)d_in[1];
  const float* Wq   = (const float*)d_in[2];
  const float* bq   = (const float*)d_in[3];
  const float* Wk   = (const float*)d_in[4];
  const float* bk   = (const float*)d_in[5];
  const float* Wv   = (const float*)d_in[6];
  const float* bv   = (const float*)d_in[7];
  float* out = (float*)d_out;

  unsigned short* xb = (unsigned short*)d_out;            // scratch, overwritten by attn out
  unsigned short* wb = xb + (size_t)NB * NS * NHID;
  unsigned short* qw = (unsigned short*)d_ws;
  unsigned short* kw = qw + (size_t)NBH * NS * NHD;
  unsigned short* vw = kw + (size_t)NBH * NS * NHD;

  cvt_kernel<<<7872, 256, 0, stream>>>(X, Wq, Wk, Wv, xb, wb);
  qkv_gemm<<<dim3(64, 18), 256, 0, stream>>>(xb, wb, bq, bk, bv, qw, kw, vw);
  attn_kernel<<<768, 256, 0, stream>>>(qw, kw, vw, mask, out);
}